// Round 8
// baseline (97.925 us; speedup 1.0000x reference)
//
#include <hip/hip_runtime.h>
#include <math.h>

// GPR_58746562675312: haversine-windowed weighted mean.
//   m[y] = sum_x w(y,x)*x[x] / sum_x w(y,x),  w = d if d<0.25 else 0,
//   d = 12.756 * asin(sqrt(hav(y,x)));  out = [m (ny), 0.001 (ny)]
//
// R8: build pipeline identical to R7 (proven). Main kernel reworked:
//  - sortedA repacked to (slat, slon, clon, xval); clat recomputed via
//    sqrt(1-slat^2) once per point (dHav ~7e-10 << 5e-8 band -> decisions
//    unchanged). One 16B load per point.
//  - 2 consecutive sorted y's per wave: point load + clat + strip setup
//    amortized 2x. 750 blocks x 256 thr.
//  - Strip-setup asin via small-angle poly (arg <= 0.0202) - no libm call.
//  - Band path (CR fp32-chain emulation, byte-equivalent to R2..R7) in a
//    noinline helper.

#define TPB    256
#define NSTRIP 40
#define NLON   40
#define NCELLS (NSTRIP * NLON)
#define C_CELL   0.25f
#define INV_CELL 4.0f
#define RLAT     1.1250f   // conservative window radius in degrees

__device__ __forceinline__ float sin_poly(float a) {
    float t = a * a;   // |a| <= 0.1746: err ~1e-9
    return a * fmaf(t, fmaf(t, 8.3333333e-3f, -0.16666667f), 1.0f);
}
__device__ __forceinline__ float cos_poly(float a) {
    float t = a * a;   // err ~2e-11
    return fmaf(t, fmaf(t, fmaf(t, -1.3888889e-3f, 4.1666668e-2f), -0.5f), 1.0f);
}
__device__ __forceinline__ int cell_of(float lon, float lat) {
    int s = (int)(lat * INV_CELL); s = min(max(s, 0), NSTRIP - 1);
    int l = (int)(lon * INV_CELL); l = min(max(l, 0), NLON - 1);
    return s * NLON + l;
}

// Rare-path: emulate the numpy fp32 chain, every step correctly rounded.
// Same op sequence as the R2..R7 inline version that passed.
__device__ __attribute__((noinline)) float band_w(float lonx, float latx,
                                                  float lony, float laty)
{
    const float d2r = 0.017453292519943295f;
    float dlat = __fsub_rn(latx, laty);
    float alat = __fmul_rn(dlat, d2r);
    float slf  = (float)sin((double)alat);        // CR fp32 sin
    float h1   = __fmul_rn(slf, slf);

    float axl  = __fmul_rn(latx, d2r);
    float ayl  = __fmul_rn(laty, d2r);
    float cxf  = (float)cos((double)axl);         // CR fp32 cos
    float cyf  = (float)cos((double)ayl);
    float cc   = __fmul_rn(cxf, cyf);

    float dlon = __fsub_rn(lonx, lony);
    float alon = __fmul_rn(dlon, d2r);
    float sdf  = (float)sin((double)alon);
    float h2   = __fmul_rn(sdf, sdf);

    float hv   = __fadd_rn(h1, __fmul_rn(cc, h2));
    float r32  = (float)sqrt((double)hv);         // CR fp32 sqrt
    float as32 = (float)asin((double)r32);        // CR fp32 asin
    float dnp  = __fmul_rn(12.756f, as32);
    return (dnp < 0.25f) ? dnp : 0.0f;
}

// ---- binning pipeline (R7-proven shapes) ------------------------------

__global__ __launch_bounds__(TPB) void zero_kernel(int* __restrict__ histX,
                                                   int* __restrict__ histY) {
    for (int i = threadIdx.x; i < NCELLS; i += TPB) { histX[i] = 0; histY[i] = 0; }
}

__global__ __launch_bounds__(TPB) void hist_kernel(
    const float* __restrict__ x_l, const float* __restrict__ y_l,
    int* __restrict__ histX, int* __restrict__ histY, int nx, int ny)
{
    int i = blockIdx.x * TPB + threadIdx.x;
    if (i < nx) {
        atomicAdd(&histX[cell_of(x_l[2 * i], x_l[2 * i + 1])], 1);
    } else if (i < nx + ny) {
        int j = i - nx;
        atomicAdd(&histY[cell_of(y_l[2 * j], y_l[2 * j + 1])], 1);
    }
}

__global__ __launch_bounds__(TPB) void scan_kernel(
    const int* __restrict__ histX, const int* __restrict__ histY,
    int* __restrict__ csX, int* __restrict__ csY,
    int* __restrict__ curX, int* __restrict__ curY)
{
    const int CHUNK = (NCELLS + TPB - 1) / TPB;   // 7
    __shared__ int sums[TPB];
    const int* hist      = (blockIdx.x == 0) ? histX : histY;
    int*       cellStart = (blockIdx.x == 0) ? csX  : csY;
    int*       cursor    = (blockIdx.x == 0) ? curX : curY;

    int tid = threadIdx.x;
    int base = tid * CHUNK;
    int local[7];
    int s = 0;
    #pragma unroll
    for (int j = 0; j < CHUNK; ++j) {
        int idx = base + j;
        int v = (idx < NCELLS) ? hist[idx] : 0;
        local[j] = s; s += v;
    }
    sums[tid] = s;
    __syncthreads();
    for (int off = 1; off < TPB; off <<= 1) {
        int t = (tid >= off) ? sums[tid - off] : 0;
        __syncthreads();
        sums[tid] += t;
        __syncthreads();
    }
    int excl = (tid > 0) ? sums[tid - 1] : 0;
    #pragma unroll
    for (int j = 0; j < CHUNK; ++j) {
        int idx = base + j;
        if (idx < NCELLS) { cellStart[idx] = excl + local[j]; cursor[idx] = excl + local[j]; }
    }
    if (tid == TPB - 1) cellStart[NCELLS] = sums[TPB - 1];
}

__global__ __launch_bounds__(TPB) void scatter_kernel(
    const float* __restrict__ x, const float* __restrict__ x_l,
    const float* __restrict__ y_l,
    int* __restrict__ curX, int* __restrict__ curY,
    float4* __restrict__ sortedA, float2* __restrict__ sortedRaw,
    float2* __restrict__ sortedYL, int* __restrict__ sortedYIdx,
    int nx, int ny)
{
    const float d2r = 0.017453292519943295f;
    int i = blockIdx.x * TPB + threadIdx.x;
    if (i < nx) {
        float lon = x_l[2 * i], lat = x_l[2 * i + 1];
        int pos = atomicAdd(&curX[cell_of(lon, lat)], 1);
        float al = lat * d2r, ao = lon * d2r;
        sortedA[pos]   = make_float4(sin_poly(al), sin_poly(ao),
                                     cos_poly(ao), x[i]);
        sortedRaw[pos] = make_float2(lon, lat);
    } else if (i < nx + ny) {
        int j = i - nx;
        float lon = y_l[2 * j], lat = y_l[2 * j + 1];
        int pos = atomicAdd(&curY[cell_of(lon, lat)], 1);
        sortedYL[pos]   = make_float2(lon, lat);
        sortedYIdx[pos] = j;
    }
}

// ---- main kernel: 2 sorted y's per wave -------------------------------

__global__ __launch_bounds__(TPB) void gpr_binned(
    const float4* __restrict__ sortedA,   // (slat, slon, clon, xval)
    const float2* __restrict__ sortedRaw, // (lon, lat) raw degrees
    const int*    __restrict__ cellStart, // [NCELLS+1] (x grid)
    const float2* __restrict__ sortedYL,
    const int*    __restrict__ sortedYIdx,
    float* __restrict__ out, int ny, float Hcut, float HcutM)
{
    const int tid  = threadIdx.x;
    const int wave = tid >> 6;
    const int lane = tid & 63;
    const int wid  = blockIdx.x * (TPB / 64) + wave;
    const int j0   = 2 * wid;
    const int j1   = j0 + 1;
    if (j0 >= ny) return;   // wave-uniform; no __syncthreads here
    const bool has1 = (j1 < ny);

    const float d2r    = 0.017453292519943295f;
    const float r2d    = 57.29577951308232f;
    const float DIAM   = 12.756f;
    const float DIAM6  = 12.756f / 6.0f;
    const float EPS_H  = 5e-8f;

    const int    yi0 = sortedYIdx[j0];
    const float2 q0  = sortedYL[j0];
    const int    yi1 = has1 ? sortedYIdx[j1] : yi0;
    const float2 q1  = has1 ? sortedYL[j1] : q0;

    const float lon0 = q0.x, lat0 = q0.y;
    const float lon1 = q1.x, lat1 = q1.y;

    const float sly0 = sin_poly(lat0 * d2r), cly0 = cos_poly(lat0 * d2r);
    const float slo0 = sin_poly(lon0 * d2r), clo0 = cos_poly(lon0 * d2r);
    const float sly1 = sin_poly(lat1 * d2r), cly1 = cos_poly(lat1 * d2r);
    const float slo1 = sin_poly(lon1 * d2r), clo1 = cos_poly(lon1 * d2r);

    float accw0 = 0.0f, accx0 = 0.0f, accw1 = 0.0f, accx1 = 0.0f;

    const float latmin = fminf(lat0, lat1), latmax = fmaxf(lat0, lat1);
    const int s0 = max(0,          (int)floorf((latmin - RLAT) * INV_CELL));
    const int s1 = min(NSTRIP - 1, (int)floorf((latmax + RLAT) * INV_CELL));

    for (int s = s0; s <= s1; ++s) {
        const float slo = s * C_CELL, shi = slo + C_CELL;
        const float ccs = cos_poly(fminf(shi, 10.0f) * d2r) * 0.999999f;

        int lo = NLON, hi = -1;
        {   // y0 window
            float dmin = fmaxf(0.0f, fmaxf(slo - lat0, lat0 - shi));
            float de   = fmaxf(0.0f, dmin - 3e-3f);
            float sp   = sin_poly(de * d2r);
            float rem  = HcutM - sp * sp;
            if (rem > 0.0f) {
                float rr = __builtin_amdgcn_sqrtf(rem / (ccs * cly0));
                float W  = rr * fmaf(rr * rr, 0.16666667f, 1.0f) * r2d + 4e-3f;
                lo = min(lo, min(NLON - 1, max(0, (int)floorf((lon0 - W) * INV_CELL))));
                hi = max(hi, min(NLON - 1, max(0, (int)floorf((lon0 + W) * INV_CELL))));
            }
        }
        {   // y1 window
            float dmin = fmaxf(0.0f, fmaxf(slo - lat1, lat1 - shi));
            float de   = fmaxf(0.0f, dmin - 3e-3f);
            float sp   = sin_poly(de * d2r);
            float rem  = HcutM - sp * sp;
            if (rem > 0.0f) {
                float rr = __builtin_amdgcn_sqrtf(rem / (ccs * cly1));
                float W  = rr * fmaf(rr * rr, 0.16666667f, 1.0f) * r2d + 4e-3f;
                lo = min(lo, min(NLON - 1, max(0, (int)floorf((lon1 - W) * INV_CELL))));
                hi = max(hi, min(NLON - 1, max(0, (int)floorf((lon1 + W) * INV_CELL))));
            }
        }
        if (hi < lo) continue;

        const int p0 = cellStart[s * NLON + lo];
        const int p1 = cellStart[s * NLON + hi + 1];

        for (int k = p0 + lane; k < p1; k += 64) {
            float4 e = sortedA[k];   // (slat_x, slon_x, clon_x, xval)
            float cl = __builtin_amdgcn_sqrtf(fmaf(-e.x, e.x, 1.0f)); // clat_x

            // ---- y0
            {
                float sl  = fmaf(e.x, cly0, -(cl * sly0));
                float sd  = fmaf(e.y, clo0, -(e.z * slo0));
                float hav = fmaf(sl, sl, (cl * cly0) * (sd * sd));
                float tb  = hav - Hcut;
                float r   = __builtin_amdgcn_sqrtf(hav);
                float d   = r * fmaf(hav, DIAM6, DIAM);
                float w;
                if (__builtin_expect(fabsf(tb) < EPS_H, 0)) {
                    float2 raw = sortedRaw[k];
                    w = band_w(raw.x, raw.y, lon0, lat0);
                } else {
                    w = (tb < 0.0f) ? d : 0.0f;
                }
                accw0 += w;
                accx0  = fmaf(w, e.w, accx0);
            }
            // ---- y1
            {
                float sl  = fmaf(e.x, cly1, -(cl * sly1));
                float sd  = fmaf(e.y, clo1, -(e.z * slo1));
                float hav = fmaf(sl, sl, (cl * cly1) * (sd * sd));
                float tb  = hav - Hcut;
                float r   = __builtin_amdgcn_sqrtf(hav);
                float d   = r * fmaf(hav, DIAM6, DIAM);
                float w;
                if (__builtin_expect(fabsf(tb) < EPS_H, 0)) {
                    float2 raw = sortedRaw[k];
                    w = band_w(raw.x, raw.y, lon1, lat1);
                } else {
                    w = (tb < 0.0f) ? d : 0.0f;
                }
                accw1 += w;
                accx1  = fmaf(w, e.w, accx1);
            }
        }
    }

    #pragma unroll
    for (int off = 32; off > 0; off >>= 1) {
        accw0 += __shfl_xor(accw0, off, 64);
        accx0 += __shfl_xor(accx0, off, 64);
        accw1 += __shfl_xor(accw1, off, 64);
        accx1 += __shfl_xor(accx1, off, 64);
    }

    if (lane == 0) {
        float m0 = (accw0 > 0.0f) ? (accx0 / fmaxf(accw0, 1e-12f)) : 0.0f;
        out[yi0]      = m0;
        out[ny + yi0] = 0.001f;
        if (has1) {
            float m1 = (accw1 > 0.0f) ? (accx1 / fmaxf(accw1, 1e-12f)) : 0.0f;
            out[yi1]      = m1;
            out[ny + yi1] = 0.001f;
        }
    }
}

// ---- fallback: full scan, used only if ws is too small ----------------

__global__ __launch_bounds__(TPB) void gpr_full(
    const float* __restrict__ x, const float* __restrict__ x_l,
    const float* __restrict__ y_l, float* __restrict__ out,
    int nx, int ny, float Hcut)
{
    const int tid  = threadIdx.x;
    const int wave = tid >> 6;
    const int lane = tid & 63;
    const int y    = blockIdx.x * 4 + wave;

    const float d2r    = 0.017453292519943295f;
    const float DIAM   = 12.756f;
    const float DIAM6  = 12.756f / 6.0f;
    const float EPS_H  = 5e-8f;

    float lon_y = 0.0f, lat_y = 0.0f;
    if (y < ny) { lon_y = y_l[2 * y]; lat_y = y_l[2 * y + 1]; }
    const float sly   = sin_poly(lat_y * d2r);
    const float cly   = cos_poly(lat_y * d2r);
    const float slony = sin_poly(lon_y * d2r);
    const float clony = cos_poly(lon_y * d2r);

    float accw = 0.0f, accwx = 0.0f;

    for (int k = lane; k < nx; k += 64) {
        float lonx = x_l[2 * k], latx = x_l[2 * k + 1];
        float xv   = x[k];
        float sl   = fmaf(sin_poly(latx * d2r), cly, -(cos_poly(latx * d2r) * sly));
        float sd   = fmaf(sin_poly(lonx * d2r), clony, -(cos_poly(lonx * d2r) * slony));
        float cxy  = cos_poly(latx * d2r) * cly;
        float hav  = fmaf(sl, sl, cxy * (sd * sd));
        float tb   = hav - Hcut;
        float r    = __builtin_amdgcn_sqrtf(hav);
        float d    = r * fmaf(hav, DIAM6, DIAM);
        float w;
        if (__builtin_expect(fabsf(tb) < EPS_H, 0)) {
            w = band_w(lonx, latx, lon_y, lat_y);
        } else {
            w = (tb < 0.0f) ? d : 0.0f;
        }
        accw += w;
        accwx = fmaf(w, xv, accwx);
    }

    #pragma unroll
    for (int off = 32; off > 0; off >>= 1) {
        accw  += __shfl_xor(accw,  off, 64);
        accwx += __shfl_xor(accwx, off, 64);
    }

    if (lane == 0 && y < ny) {
        float m = (accw > 0.0f) ? (accwx / fmaxf(accw, 1e-12f)) : 0.0f;
        out[y]      = m;
        out[ny + y] = 0.001f;
    }
}

// ---- launcher ----------------------------------------------------------

extern "C" void kernel_launch(void* const* d_in, const int* in_sizes, int n_in,
                              void* d_out, int out_size, void* d_ws, size_t ws_size,
                              hipStream_t stream) {
    const float* x   = (const float*)d_in[0];
    const float* x_l = (const float*)d_in[1];
    const float* y_l = (const float*)d_in[2];
    float* out = (float*)d_out;

    const int nx = in_sizes[0];        // 20000
    const int ny = in_sizes[2] / 2;    // 6000

    // hav threshold, fp64 on host: sin^2(0.25/12.756)
    double th = 0.25 / 12.756;
    double s  = sin(th);
    float Hcut  = (float)(s * s);
    float HcutM = (float)(s * s * 1.001);   // margin for window pruning

    // ws layout
    size_t offA   = 0;
    size_t offRaw = offA   + (size_t)nx * sizeof(float4);       // 16 nx
    size_t offYL  = offRaw + (size_t)nx * sizeof(float2);       //  8 nx
    size_t offYI  = offYL  + (size_t)ny * sizeof(float2);       //  8 ny
    size_t offHX  = offYI  + (size_t)ny * sizeof(int);          //  4 ny
    size_t offHY  = offHX  + (size_t)NCELLS * sizeof(int);
    size_t offCSX = offHY  + (size_t)NCELLS * sizeof(int);
    size_t offCSY = offCSX + (size_t)(NCELLS + 1) * sizeof(int);
    size_t offCuX = offCSY + (size_t)(NCELLS + 1) * sizeof(int);
    size_t offCuY = offCuX + (size_t)NCELLS * sizeof(int);
    size_t total  = offCuY + (size_t)NCELLS * sizeof(int);

    if (ws_size >= total) {
        float4* sortedA    = (float4*)((char*)d_ws + offA);
        float2* sortedRaw  = (float2*)((char*)d_ws + offRaw);
        float2* sortedYL   = (float2*)((char*)d_ws + offYL);
        int*    sortedYIdx = (int*)   ((char*)d_ws + offYI);
        int*    histX      = (int*)   ((char*)d_ws + offHX);
        int*    histY      = (int*)   ((char*)d_ws + offHY);
        int*    csX        = (int*)   ((char*)d_ws + offCSX);
        int*    csY        = (int*)   ((char*)d_ws + offCSY);
        int*    curX       = (int*)   ((char*)d_ws + offCuX);
        int*    curY       = (int*)   ((char*)d_ws + offCuY);

        int nb = (nx + ny + TPB - 1) / TPB;
        zero_kernel<<<1, TPB, 0, stream>>>(histX, histY);
        hist_kernel<<<nb, TPB, 0, stream>>>(x_l, y_l, histX, histY, nx, ny);
        scan_kernel<<<2, TPB, 0, stream>>>(histX, histY, csX, csY, curX, curY);
        scatter_kernel<<<nb, TPB, 0, stream>>>(x, x_l, y_l, curX, curY,
                                               sortedA, sortedRaw,
                                               sortedYL, sortedYIdx, nx, ny);
        int nwaves = (ny + 1) / 2;
        int blocks = (nwaves + (TPB / 64) - 1) / (TPB / 64);
        gpr_binned<<<blocks, TPB, 0, stream>>>(sortedA, sortedRaw, csX,
                                               sortedYL, sortedYIdx,
                                               out, ny, Hcut, HcutM);
    } else {
        int blocks = (ny + 3) / 4;
        gpr_full<<<blocks, TPB, 0, stream>>>(x, x_l, y_l, out, nx, ny, Hcut);
    }
}

// Round 9
// 94.295 us; speedup vs baseline: 1.0385x; 1.0385x over previous
//
#include <hip/hip_runtime.h>
#include <math.h>

// GPR_58746562675312: haversine-windowed weighted mean.
//   m[y] = sum_x w(y,x)*x[x] / sum_x w(y,x),  w = d if d<0.25 else 0,
//   d = 12.756 * asin(sqrt(hav(y,x)));  out = [m (ny), 0.001 (ny)]
//
// R9: strip-level parallelism. R7's main kernel was latency-bound: 10
// serial strips per y-wave, each ~2.4 inner iterations of dependent L2
// loads, ~6 waves/SIMD. Now one wave per (y, strip-slot): s1-s0 == 9
// always (RLAT margin 1.125-1.12292=2e-3 deg >> fp32 rounding), so 10
// slots cover all contributing strips. 60000 waves saturate all SIMD
// wave slots; each writes a deterministic partial (no atomics); a small
// reduce kernel finalizes. Build pipeline (zero/hist/scan/scatter) and
// CR band path byte-identical to R7/R8 (proven). 16B packed sortedA
// (slat, slon, clon, xval) + clat recompute proven in R8.

#define TPB    256
#define NSLOT  10
#define NSTRIP 40
#define NLON   40
#define NCELLS (NSTRIP * NLON)
#define C_CELL   0.25f
#define INV_CELL 4.0f
#define RLAT     1.1250f   // conservative window radius in degrees

__device__ __forceinline__ float sin_poly(float a) {
    float t = a * a;   // |a| <= 0.1746: err ~1e-9
    return a * fmaf(t, fmaf(t, 8.3333333e-3f, -0.16666667f), 1.0f);
}
__device__ __forceinline__ float cos_poly(float a) {
    float t = a * a;   // err ~2e-11
    return fmaf(t, fmaf(t, fmaf(t, -1.3888889e-3f, 4.1666668e-2f), -0.5f), 1.0f);
}
__device__ __forceinline__ int cell_of(float lon, float lat) {
    int s = (int)(lat * INV_CELL); s = min(max(s, 0), NSTRIP - 1);
    int l = (int)(lon * INV_CELL); l = min(max(l, 0), NLON - 1);
    return s * NLON + l;
}

// Rare-path: emulate the numpy fp32 chain, every step correctly rounded.
// Same op sequence as the R2..R8 version that passed.
__device__ __attribute__((noinline)) float band_w(float lonx, float latx,
                                                  float lony, float laty)
{
    const float d2r = 0.017453292519943295f;
    float dlat = __fsub_rn(latx, laty);
    float alat = __fmul_rn(dlat, d2r);
    float slf  = (float)sin((double)alat);        // CR fp32 sin
    float h1   = __fmul_rn(slf, slf);

    float axl  = __fmul_rn(latx, d2r);
    float ayl  = __fmul_rn(laty, d2r);
    float cxf  = (float)cos((double)axl);         // CR fp32 cos
    float cyf  = (float)cos((double)ayl);
    float cc   = __fmul_rn(cxf, cyf);

    float dlon = __fsub_rn(lonx, lony);
    float alon = __fmul_rn(dlon, d2r);
    float sdf  = (float)sin((double)alon);
    float h2   = __fmul_rn(sdf, sdf);

    float hv   = __fadd_rn(h1, __fmul_rn(cc, h2));
    float r32  = (float)sqrt((double)hv);         // CR fp32 sqrt
    float as32 = (float)asin((double)r32);        // CR fp32 asin
    float dnp  = __fmul_rn(12.756f, as32);
    return (dnp < 0.25f) ? dnp : 0.0f;
}

// ---- binning pipeline (R7-proven shapes) ------------------------------

__global__ __launch_bounds__(TPB) void zero_kernel(int* __restrict__ histX,
                                                   int* __restrict__ histY) {
    for (int i = threadIdx.x; i < NCELLS; i += TPB) { histX[i] = 0; histY[i] = 0; }
}

__global__ __launch_bounds__(TPB) void hist_kernel(
    const float* __restrict__ x_l, const float* __restrict__ y_l,
    int* __restrict__ histX, int* __restrict__ histY, int nx, int ny)
{
    int i = blockIdx.x * TPB + threadIdx.x;
    if (i < nx) {
        atomicAdd(&histX[cell_of(x_l[2 * i], x_l[2 * i + 1])], 1);
    } else if (i < nx + ny) {
        int j = i - nx;
        atomicAdd(&histY[cell_of(y_l[2 * j], y_l[2 * j + 1])], 1);
    }
}

__global__ __launch_bounds__(TPB) void scan_kernel(
    const int* __restrict__ histX, const int* __restrict__ histY,
    int* __restrict__ csX, int* __restrict__ csY,
    int* __restrict__ curX, int* __restrict__ curY)
{
    const int CHUNK = (NCELLS + TPB - 1) / TPB;   // 7
    __shared__ int sums[TPB];
    const int* hist      = (blockIdx.x == 0) ? histX : histY;
    int*       cellStart = (blockIdx.x == 0) ? csX  : csY;
    int*       cursor    = (blockIdx.x == 0) ? curX : curY;

    int tid = threadIdx.x;
    int base = tid * CHUNK;
    int local[7];
    int s = 0;
    #pragma unroll
    for (int j = 0; j < CHUNK; ++j) {
        int idx = base + j;
        int v = (idx < NCELLS) ? hist[idx] : 0;
        local[j] = s; s += v;
    }
    sums[tid] = s;
    __syncthreads();
    for (int off = 1; off < TPB; off <<= 1) {
        int t = (tid >= off) ? sums[tid - off] : 0;
        __syncthreads();
        sums[tid] += t;
        __syncthreads();
    }
    int excl = (tid > 0) ? sums[tid - 1] : 0;
    #pragma unroll
    for (int j = 0; j < CHUNK; ++j) {
        int idx = base + j;
        if (idx < NCELLS) { cellStart[idx] = excl + local[j]; cursor[idx] = excl + local[j]; }
    }
    if (tid == TPB - 1) cellStart[NCELLS] = sums[TPB - 1];
}

__global__ __launch_bounds__(TPB) void scatter_kernel(
    const float* __restrict__ x, const float* __restrict__ x_l,
    const float* __restrict__ y_l,
    int* __restrict__ curX, int* __restrict__ curY,
    float4* __restrict__ sortedA, float2* __restrict__ sortedRaw,
    float2* __restrict__ sortedYL, int* __restrict__ sortedYIdx,
    int nx, int ny)
{
    const float d2r = 0.017453292519943295f;
    int i = blockIdx.x * TPB + threadIdx.x;
    if (i < nx) {
        float lon = x_l[2 * i], lat = x_l[2 * i + 1];
        int pos = atomicAdd(&curX[cell_of(lon, lat)], 1);
        float al = lat * d2r, ao = lon * d2r;
        sortedA[pos]   = make_float4(sin_poly(al), sin_poly(ao),
                                     cos_poly(ao), x[i]);
        sortedRaw[pos] = make_float2(lon, lat);
    } else if (i < nx + ny) {
        int j = i - nx;
        float lon = y_l[2 * j], lat = y_l[2 * j + 1];
        int pos = atomicAdd(&curY[cell_of(lon, lat)], 1);
        sortedYL[pos]   = make_float2(lon, lat);
        sortedYIdx[pos] = j;
    }
}

// ---- main kernel: one wave per (sorted-y, strip-slot) -----------------

__global__ __launch_bounds__(TPB) void gpr_strip(
    const float4* __restrict__ sortedA,   // (slat, slon, clon, xval)
    const float2* __restrict__ sortedRaw, // (lon, lat) raw degrees
    const int*    __restrict__ cellStart, // [NCELLS+1] (x grid)
    const float2* __restrict__ sortedYL,
    float2* __restrict__ partial,         // [ny*NSLOT] (sum_w, sum_wx)
    int ny, float Hcut, float HcutM)
{
    const int lane = threadIdx.x & 63;
    const int wid  = blockIdx.x * (TPB / 64) + (threadIdx.x >> 6);
    const int j    = wid / NSLOT;
    const int slot = wid - j * NSLOT;
    if (j >= ny) return;   // wave-uniform

    const float d2r   = 0.017453292519943295f;
    const float r2d   = 57.29577951308232f;
    const float DIAM  = 12.756f;
    const float DIAM6 = 12.756f / 6.0f;
    const float EPS_H = 5e-8f;

    const float2 q     = sortedYL[j];
    const float  lon_y = q.x, lat_y = q.y;

    float accw = 0.0f, accx = 0.0f;

    const int s = (int)floorf((lat_y - RLAT) * INV_CELL) + slot;
    if (s >= 0 && s < NSTRIP) {
        const float sly = sin_poly(lat_y * d2r);
        const float cly = cos_poly(lat_y * d2r);
        const float slo = sin_poly(lon_y * d2r);
        const float clo = cos_poly(lon_y * d2r);

        // conservative min |dlat| from y to this strip (R7-proven)
        const float strip_lo = s * C_CELL, strip_hi = strip_lo + C_CELL;
        float dmin = fmaxf(0.0f, fmaxf(strip_lo - lat_y, lat_y - strip_hi));
        float de   = fmaxf(0.0f, dmin - 3e-3f);
        float sp   = sin_poly(de * d2r);
        float rem  = HcutM - sp * sp;
        if (rem > 0.0f) {
            float ccm = cos_poly(fminf(strip_hi, 10.0f) * d2r) * cly * 0.999999f;
            float rr  = __builtin_amdgcn_sqrtf(rem / ccm);
            float W   = rr * fmaf(rr * rr, 0.16666667f, 1.0f) * r2d + 4e-3f;
            int lo = min(NLON - 1, max(0, (int)floorf((lon_y - W) * INV_CELL)));
            int hi = min(NLON - 1, max(0, (int)floorf((lon_y + W) * INV_CELL)));
            int p0 = cellStart[s * NLON + lo];
            int p1 = cellStart[s * NLON + hi + 1];

            for (int k = p0 + lane; k < p1; k += 64) {
                float4 e = sortedA[k];   // (slat_x, slon_x, clon_x, xval)
                float cl = __builtin_amdgcn_sqrtf(fmaf(-e.x, e.x, 1.0f));

                float sl  = fmaf(e.x, cly, -(cl * sly));
                float sd  = fmaf(e.y, clo, -(e.z * slo));
                float hav = fmaf(sl, sl, (cl * cly) * (sd * sd));
                float tb  = hav - Hcut;
                float r   = __builtin_amdgcn_sqrtf(hav);
                float d   = r * fmaf(hav, DIAM6, DIAM);
                float w;
                if (__builtin_expect(fabsf(tb) < EPS_H, 0)) {
                    float2 raw = sortedRaw[k];
                    w = band_w(raw.x, raw.y, lon_y, lat_y);
                } else {
                    w = (tb < 0.0f) ? d : 0.0f;
                }
                accw += w;
                accx  = fmaf(w, e.w, accx);
            }
        }
    }

    #pragma unroll
    for (int off = 32; off > 0; off >>= 1) {
        accw += __shfl_xor(accw, off, 64);
        accx += __shfl_xor(accx, off, 64);
    }

    if (lane == 0) partial[wid] = make_float2(accw, accx);  // ALWAYS write
}

__global__ __launch_bounds__(TPB) void reduce_kernel(
    const float2* __restrict__ partial, const int* __restrict__ sortedYIdx,
    float* __restrict__ out, int ny)
{
    int j = blockIdx.x * TPB + threadIdx.x;
    if (j >= ny) return;
    float w = 0.0f, wx = 0.0f;
    #pragma unroll
    for (int s = 0; s < NSLOT; ++s) {
        float2 p = partial[j * NSLOT + s];
        w += p.x; wx += p.y;
    }
    float m = (w > 0.0f) ? (wx / fmaxf(w, 1e-12f)) : 0.0f;
    int yi = sortedYIdx[j];
    out[yi]      = m;
    out[ny + yi] = 0.001f;
}

// ---- fallback: full scan, used only if ws is too small ----------------

__global__ __launch_bounds__(TPB) void gpr_full(
    const float* __restrict__ x, const float* __restrict__ x_l,
    const float* __restrict__ y_l, float* __restrict__ out,
    int nx, int ny, float Hcut)
{
    const int tid  = threadIdx.x;
    const int wave = tid >> 6;
    const int lane = tid & 63;
    const int y    = blockIdx.x * 4 + wave;

    const float d2r   = 0.017453292519943295f;
    const float DIAM  = 12.756f;
    const float DIAM6 = 12.756f / 6.0f;
    const float EPS_H = 5e-8f;

    float lon_y = 0.0f, lat_y = 0.0f;
    if (y < ny) { lon_y = y_l[2 * y]; lat_y = y_l[2 * y + 1]; }
    const float sly   = sin_poly(lat_y * d2r);
    const float cly   = cos_poly(lat_y * d2r);
    const float slony = sin_poly(lon_y * d2r);
    const float clony = cos_poly(lon_y * d2r);

    float accw = 0.0f, accwx = 0.0f;

    for (int k = lane; k < nx; k += 64) {
        float lonx = x_l[2 * k], latx = x_l[2 * k + 1];
        float xv   = x[k];
        float sl   = fmaf(sin_poly(latx * d2r), cly, -(cos_poly(latx * d2r) * sly));
        float sd   = fmaf(sin_poly(lonx * d2r), clony, -(cos_poly(lonx * d2r) * slony));
        float cxy  = cos_poly(latx * d2r) * cly;
        float hav  = fmaf(sl, sl, cxy * (sd * sd));
        float tb   = hav - Hcut;
        float r    = __builtin_amdgcn_sqrtf(hav);
        float d    = r * fmaf(hav, DIAM6, DIAM);
        float w;
        if (__builtin_expect(fabsf(tb) < EPS_H, 0)) {
            w = band_w(lonx, latx, lon_y, lat_y);
        } else {
            w = (tb < 0.0f) ? d : 0.0f;
        }
        accw += w;
        accwx = fmaf(w, xv, accwx);
    }

    #pragma unroll
    for (int off = 32; off > 0; off >>= 1) {
        accw  += __shfl_xor(accw,  off, 64);
        accwx += __shfl_xor(accwx, off, 64);
    }

    if (lane == 0 && y < ny) {
        float m = (accw > 0.0f) ? (accwx / fmaxf(accw, 1e-12f)) : 0.0f;
        out[y]      = m;
        out[ny + y] = 0.001f;
    }
}

// ---- launcher ----------------------------------------------------------

extern "C" void kernel_launch(void* const* d_in, const int* in_sizes, int n_in,
                              void* d_out, int out_size, void* d_ws, size_t ws_size,
                              hipStream_t stream) {
    const float* x   = (const float*)d_in[0];
    const float* x_l = (const float*)d_in[1];
    const float* y_l = (const float*)d_in[2];
    float* out = (float*)d_out;

    const int nx = in_sizes[0];        // 20000
    const int ny = in_sizes[2] / 2;    // 6000

    // hav threshold, fp64 on host: sin^2(0.25/12.756)
    double th = 0.25 / 12.756;
    double s  = sin(th);
    float Hcut  = (float)(s * s);
    float HcutM = (float)(s * s * 1.001);   // margin for window pruning

    // ws layout
    size_t offA   = 0;
    size_t offRaw = offA   + (size_t)nx * sizeof(float4);          // 16 nx
    size_t offYL  = offRaw + (size_t)nx * sizeof(float2);          //  8 nx
    size_t offPar = offYL  + (size_t)ny * sizeof(float2);          //  8 ny
    size_t offYI  = offPar + (size_t)ny * NSLOT * sizeof(float2);  // 80 ny
    size_t offHX  = offYI  + (size_t)ny * sizeof(int);             //  4 ny
    size_t offHY  = offHX  + (size_t)NCELLS * sizeof(int);
    size_t offCSX = offHY  + (size_t)NCELLS * sizeof(int);
    size_t offCSY = offCSX + (size_t)(NCELLS + 1) * sizeof(int);
    size_t offCuX = offCSY + (size_t)(NCELLS + 1) * sizeof(int);
    size_t offCuY = offCuX + (size_t)NCELLS * sizeof(int);
    size_t total  = offCuY + (size_t)NCELLS * sizeof(int);

    if (ws_size >= total) {
        float4* sortedA    = (float4*)((char*)d_ws + offA);
        float2* sortedRaw  = (float2*)((char*)d_ws + offRaw);
        float2* sortedYL   = (float2*)((char*)d_ws + offYL);
        float2* partial    = (float2*)((char*)d_ws + offPar);
        int*    sortedYIdx = (int*)   ((char*)d_ws + offYI);
        int*    histX      = (int*)   ((char*)d_ws + offHX);
        int*    histY      = (int*)   ((char*)d_ws + offHY);
        int*    csX        = (int*)   ((char*)d_ws + offCSX);
        int*    csY        = (int*)   ((char*)d_ws + offCSY);
        int*    curX       = (int*)   ((char*)d_ws + offCuX);
        int*    curY       = (int*)   ((char*)d_ws + offCuY);

        int nb = (nx + ny + TPB - 1) / TPB;
        zero_kernel<<<1, TPB, 0, stream>>>(histX, histY);
        hist_kernel<<<nb, TPB, 0, stream>>>(x_l, y_l, histX, histY, nx, ny);
        scan_kernel<<<2, TPB, 0, stream>>>(histX, histY, csX, csY, curX, curY);
        scatter_kernel<<<nb, TPB, 0, stream>>>(x, x_l, y_l, curX, curY,
                                               sortedA, sortedRaw,
                                               sortedYL, sortedYIdx, nx, ny);
        int nwaves  = ny * NSLOT;                       // 60000
        int wblocks = (nwaves + (TPB / 64) - 1) / (TPB / 64);
        gpr_strip<<<wblocks, TPB, 0, stream>>>(sortedA, sortedRaw, csX,
                                               sortedYL, partial,
                                               ny, Hcut, HcutM);
        int rblocks = (ny + TPB - 1) / TPB;
        reduce_kernel<<<rblocks, TPB, 0, stream>>>(partial, sortedYIdx, out, ny);
    } else {
        int blocks = (ny + 3) / 4;
        gpr_full<<<blocks, TPB, 0, stream>>>(x, x_l, y_l, out, nx, ny, Hcut);
    }
}